// Round 1
// baseline (178.494 us; speedup 1.0000x reference)
//
#include <hip/hip_runtime.h>

#define N_ROWS 8192
#define NX     4096
#define DIM    512
#define BT     128          // block tile (rows & cols)
#define NT     64           // N_ROWS / BT tiles per side
#define BK     32           // K elements per stage (64 B per row)

typedef __bf16 bf16_t;
typedef bf16_t bf16x8 __attribute__((ext_vector_type(8)));
typedef bf16_t bf16x4 __attribute__((ext_vector_type(4)));
typedef float  f32x4  __attribute__((ext_vector_type(4)));

#if __has_builtin(__builtin_amdgcn_exp2f)
  #define EXP2F __builtin_amdgcn_exp2f
#else
  #define EXP2F exp2f
#endif

// ws layout (bytes):
//   0       sqrow[8192]  float   (32768 B)   exact fp32 row norms
//   32768   colsum[512]  float   ( 2048 B)
//   34816   cvals[5]     float   (   20 B)   cvals[k] = -log2e/(bw*mult_k)
//   34840   acc          double  (    8 B)
//   36864   Zh[8192*512] bf16    (8388608 B) bf16 copy of concat(X,Y)

__device__ __forceinline__ const float* zrow(const float* X, const float* Y, int r) {
    return (r < NX) ? (X + (size_t)r * DIM) : (Y + (size_t)(r - NX) * DIM);
}

// async 16B global -> LDS (lane-contiguous dest: ldsbase + lane*16)
__device__ __forceinline__ void gload_lds16(const bf16_t* g, bf16_t* l) {
    __builtin_amdgcn_global_load_lds(
        (__attribute__((address_space(1))) void*)(void*)(g),
        (__attribute__((address_space(3))) void*)(void*)(l), 16, 0, 0);
}

// fused: bf16 copy + exact fp32 row norms + colsum zero-init. 4 rows/block.
// lane owns 8 contiguous cols -> single 16B bf16x8 store.
__global__ void k_prep(const float* __restrict__ X, const float* __restrict__ Y,
                       bf16_t* __restrict__ Zh, float* __restrict__ sqrow,
                       float* __restrict__ colsum) {
    int t = threadIdx.x;
    if (blockIdx.x == 0) { colsum[t] = 0.f; colsum[t + 256] = 0.f; }
    int wv = t >> 6, lane = t & 63;
    int row = blockIdx.x * 4 + wv;
    const float4* z4 = (const float4*)zrow(X, Y, row);
    float4 a = z4[lane * 2], b = z4[lane * 2 + 1];
    bf16x8 h;
    h[0] = (bf16_t)a.x; h[1] = (bf16_t)a.y; h[2] = (bf16_t)a.z; h[3] = (bf16_t)a.w;
    h[4] = (bf16_t)b.x; h[5] = (bf16_t)b.y; h[6] = (bf16_t)b.z; h[7] = (bf16_t)b.w;
    *(bf16x8*)(Zh + (size_t)row * DIM + lane * 8) = h;
    float s = a.x*a.x + a.y*a.y + a.z*a.z + a.w*a.w
            + b.x*b.x + b.y*b.y + b.z*b.z + b.w*b.w;
    #pragma unroll
    for (int off = 32; off > 0; off >>= 1) s += __shfl_down(s, off);
    if (lane == 0) sqrow[row] = s;
}

// colsum from bf16 Zh (8 MB, half the fp32 traffic; bw error ~4e-8 relative).
// 256 blocks x 32 rows; one wave reads one full row/iter (16B/lane coalesced).
__global__ __launch_bounds__(256) void k_colsum(const bf16_t* __restrict__ Zh,
                                                float* __restrict__ colsum) {
    __shared__ float cp[4][512];
    int t = threadIdx.x, lane = t & 63, wv = t >> 6;
    int r0 = blockIdx.x * 32;
    float s[8] = {0.f, 0.f, 0.f, 0.f, 0.f, 0.f, 0.f, 0.f};
    #pragma unroll
    for (int it = 0; it < 8; ++it) {
        int row = r0 + it * 4 + wv;
        bf16x8 v = *(const bf16x8*)(Zh + (size_t)row * DIM + lane * 8);
        #pragma unroll
        for (int j = 0; j < 8; ++j) s[j] += (float)v[j];
    }
    float4 lo = {s[0], s[1], s[2], s[3]};
    float4 hi = {s[4], s[5], s[6], s[7]};
    *(float4*)&cp[wv][lane * 8]     = lo;
    *(float4*)&cp[wv][lane * 8 + 4] = hi;
    __syncthreads();
    #pragma unroll
    for (int j = 0; j < 2; ++j) {
        int c = t * 2 + j;
        atomicAdd(&colsum[c], cp[0][c] + cp[1][c] + cp[2][c] + cp[3][c]);
    }
}

// bw = (2n*S1 - 2*||colsum||^2) / (n^2 - n); write exp2 constants; zero acc
__global__ void k_bw(const float* sqrow, const float* colsum, float* cvals, double* acc) {
    __shared__ double red[256];
    int t = threadIdx.x;
    double s1 = 0.0;
    for (int i = t; i < N_ROWS; i += 256) s1 += (double)sqrow[i];
    double cs = 0.0;
    for (int d = t; d < DIM; d += 256) { double v = colsum[d]; cs += v * v; }
    red[t] = s1; __syncthreads();
    for (int off = 128; off > 0; off >>= 1) { if (t < off) red[t] += red[t + off]; __syncthreads(); }
    double S1 = red[0]; __syncthreads();
    red[t] = cs; __syncthreads();
    for (int off = 128; off > 0; off >>= 1) { if (t < off) red[t] += red[t + off]; __syncthreads(); }
    if (t == 0) {
        double CS = red[0];
        double n = (double)N_ROWS;
        double sumD2 = 2.0 * n * S1 - 2.0 * CS;
        double bw = sumD2 / (n * n - n);
        const double LOG2E = 1.4426950408889634;
        double mult = 0.25;
        for (int k = 0; k < 5; ++k) {
            cvals[k] = (float)(-LOG2E / (bw * mult));
            mult *= 2.0;
        }
        *acc = 0.0;
    }
}

// 128x128 tile over upper triangle; DOUBLE-BUFFERED 2-phase K-loop:
// issue next-tile global_load_lds BEFORE ds_read+MFMA of current tile,
// ONE __syncthreads (vmcnt(0)+lgkmcnt(0)+barrier) per K-step. Race-free:
// the barrier both publishes the just-staged buffer and separates all
// waves' reads of buf[cur^1] (iter s-1, drained by lgkmcnt) from the
// stage into buf[cur^1] at iter s.
// Layouts (m89/m91): A[m=lane&15][k=(lane>>4)*8+j]; C/D col=lane&15,
// row=(lane>>4)*4+reg. XOR swizzle on the GLOBAL side keeps frag
// ds_read_b128 conflict-free (global_load_lds dest must stay linear).
__global__ __launch_bounds__(256) void k_pair(const bf16_t* __restrict__ Zh,
                                              const float* __restrict__ sqrow,
                                              const float* __restrict__ cvals,
                                              double* acc) {
    int ti = blockIdx.x, tj = blockIdx.y;
    if (tj < ti) return;
    __shared__ bf16_t As[2][4096];   // 2 x 8 KB
    __shared__ bf16_t Bs[2][4096];
    __shared__ float wsum[4];

    int t = threadIdx.x, lane = t & 63, wv = t >> 6;
    int wr = wv >> 1, wc = wv & 1;

    // staging: issue h covers chunks h*256+t; chunk c: row r=c>>2, phys slot
    // sq=c&3 holds logical chunk q = sq ^ ((r>>1)&3)  (64 B-coalesced per row)
    const bf16_t* gA[2]; const bf16_t* gB[2];
    int ldsoff[2];
    #pragma unroll
    for (int h = 0; h < 2; ++h) {
        int c = h * 256 + t;
        int r = c >> 2, sq = c & 3;
        int q = sq ^ ((r >> 1) & 3);
        gA[h] = Zh + (size_t)(ti * BT + r) * DIM + q * 8;
        gB[h] = Zh + (size_t)(tj * BT + r) * DIM + q * 8;
        ldsoff[h] = (h * 256 + wv * 64) * 8;   // wave-uniform; lane*16B implicit
    }

    // fragment LDS element offsets (row r, logical k-chunk q16 -> phys slot)
    int n16 = lane & 15, q16 = lane >> 4;
    int aoff[4], boff[4];
    #pragma unroll
    for (int aa = 0; aa < 4; ++aa) {
        int r = 16 * (wr * 4 + aa) + n16;
        aoff[aa] = (r * 4 + (q16 ^ ((r >> 1) & 3))) * 8;
    }
    #pragma unroll
    for (int bb = 0; bb < 4; ++bb) {
        int r = 16 * (wc * 4 + bb) + n16;
        boff[bb] = (r * 4 + (q16 ^ ((r >> 1) & 3))) * 8;
    }

    f32x4 accf[4][4];
    #pragma unroll
    for (int a = 0; a < 4; ++a)
        #pragma unroll
        for (int b = 0; b < 4; ++b)
            accf[a][b] = (f32x4){0.f, 0.f, 0.f, 0.f};

    // prologue: stage K-step 0 into buffer 0
    #pragma unroll
    for (int h = 0; h < 2; ++h) {
        gload_lds16(gA[h], &As[0][ldsoff[h]]);
        gload_lds16(gB[h], &Bs[0][ldsoff[h]]);
    }
    __syncthreads();   // vmcnt(0) drain -> buf0 visible

    #pragma unroll 2
    for (int s = 0; s < DIM / BK; ++s) {
        int cur = s & 1;
        if (s + 1 < DIM / BK) {        // prefetch next K-step into other buffer
            int kn = (s + 1) * BK;
            #pragma unroll
            for (int h = 0; h < 2; ++h) {
                gload_lds16(gA[h] + kn, &As[cur ^ 1][ldsoff[h]]);
                gload_lds16(gB[h] + kn, &Bs[cur ^ 1][ldsoff[h]]);
            }
        }
        const bf16_t* Ab = As[cur];
        const bf16_t* Bb = Bs[cur];
        bf16x8 a[4], b[4];
        #pragma unroll
        for (int aa = 0; aa < 4; ++aa) a[aa] = *(const bf16x8*)(Ab + aoff[aa]);
        #pragma unroll
        for (int bb = 0; bb < 4; ++bb) b[bb] = *(const bf16x8*)(Bb + boff[bb]);
        #pragma unroll
        for (int aa = 0; aa < 4; ++aa)
            #pragma unroll
            for (int bb = 0; bb < 4; ++bb)
                accf[aa][bb] = __builtin_amdgcn_mfma_f32_16x16x32_bf16(
                    a[aa], b[bb], accf[aa][bb], 0, 0, 0);
        __syncthreads();   // drains next-stage vmcnt + publishes; guards reuse
    }

    // epilogue: D2 -> 5-bandwidth RBF via squaring chain:
    // c_k halves per k => e_k = e4^(2^(4-k)); 1 exp + 4 muls per d2
    float c4 = cvals[4];
    int i0 = ti * BT + wr * 64;
    int j0 = tj * BT + wc * 64;

    float sqi[4][4], sqj[4];
    #pragma unroll
    for (int aa = 0; aa < 4; ++aa)
        #pragma unroll
        for (int r = 0; r < 4; ++r)
            sqi[aa][r] = sqrow[i0 + 16 * aa + q16 * 4 + r];
    #pragma unroll
    for (int bb = 0; bb < 4; ++bb)
        sqj[bb] = sqrow[j0 + 16 * bb + n16];

    float s_local = 0.f;
    #pragma unroll
    for (int aa = 0; aa < 4; ++aa) {
        #pragma unroll
        for (int bb = 0; bb < 4; ++bb) {
            #pragma unroll
            for (int r = 0; r < 4; ++r) {
                float d2 = fmaf(-2.f, accf[aa][bb][r], sqi[aa][r] + sqj[bb]);
                d2 = fmaxf(d2, 0.f);
                float e4 = EXP2F(d2 * c4);       // smallest |c|
                float e3 = e4 * e4;
                float e2 = e3 * e3;
                float e1 = e2 * e2;
                float e0 = e1 * e1;
                s_local += e4 + e3 + e2 + e1 + e0;
            }
        }
    }
    #pragma unroll
    for (int off = 32; off > 0; off >>= 1) s_local += __shfl_down(s_local, off);
    if (lane == 0) wsum[wv] = s_local;
    __syncthreads();
    if (t == 0) {
        float bs = wsum[0] + wsum[1] + wsum[2] + wsum[3];
        double si = (ti < NT / 2) ? 1.0 : -1.0;
        double sj = (tj < NT / 2) ? 1.0 : -1.0;
        double w = si * sj * ((ti == tj) ? 1.0 : 2.0);
        atomicAdd(acc, w * (double)bs);
    }
}

__global__ void k_final(const double* acc, float* out) {
    out[0] = (float)(*acc / ((double)NX * (double)NX));
}

extern "C" void kernel_launch(void* const* d_in, const int* in_sizes, int n_in,
                              void* d_out, int out_size, void* d_ws, size_t ws_size,
                              hipStream_t stream) {
    const float* X = (const float*)d_in[0];
    const float* Y = (const float*)d_in[1];
    float* out = (float*)d_out;

    float*  sqrow  = (float*)d_ws;
    float*  colsum = sqrow + 8192;
    float*  cvals  = (float*)((char*)d_ws + 34816);
    double* acc    = (double*)((char*)d_ws + 34840);
    bf16_t* Zh     = (bf16_t*)((char*)d_ws + 36864);

    k_prep  <<<2048, 256, 0, stream>>>(X, Y, Zh, sqrow, colsum);
    k_colsum<<<256, 256, 0, stream>>>(Zh, colsum);
    k_bw    <<<1, 256, 0, stream>>>(sqrow, colsum, cvals, acc);
    k_pair  <<<dim3(NT, NT), 256, 0, stream>>>(Zh, sqrow, cvals, acc);
    k_final <<<1, 1, 0, stream>>>(acc, out);
}